// Round 2
// baseline (6778.609 us; speedup 1.0000x reference)
//
#include <hip/hip_runtime.h>
#include <cmath>

#define T_STEPS 256
#define DIN  1024
#define DHID 1024
#define DOUT 1024
#define NB   128
#define BH   (DHID*NB)   // 131072 elems per h snapshot

typedef unsigned short u16;
typedef unsigned int   u32;
typedef __attribute__((ext_vector_type(8))) __bf16 bf16x8;
typedef __attribute__((ext_vector_type(4))) float  f32x4;

__device__ __forceinline__ u16 f2bf(float f){
  u32 u = __builtin_bit_cast(u32, f);
  u32 r = (u + 0x7fffu + ((u >> 16) & 1u)) >> 16;   // RNE
  return (u16)r;
}
__device__ __forceinline__ float bf2f(u16 h){
  u32 u = ((u32)h) << 16;
  return __builtin_bit_cast(float, u);
}

// ---------------- weight convert: 3x 1024x1024 fp32 -> bf16 ----------------
__global__ __launch_bounds__(256) void wconv(const float* __restrict__ w0,
                                             const float* __restrict__ w1,
                                             const float* __restrict__ w2,
                                             u16* __restrict__ dst){
  const int idx = blockIdx.x*256 + threadIdx.x;   // < 786432 (float4 units)
  const int seg = idx >> 18;                      // /262144
  const int off = idx & 262143;
  const float* src = seg==0 ? w0 : (seg==1 ? w1 : w2);
  const float4 v = ((const float4*)src)[off];
  ushort4 o = make_ushort4(f2bf(v.x), f2bf(v.y), f2bf(v.z), f2bf(v.w));
  ((ushort4*)dst)[idx] = o;
}

// ---------------- h_prev [HID][B] fp32 -> H_T[0] [B][HID] bf16 ----------------
__global__ __launch_bounds__(256) void hprevT(const float* __restrict__ hp,
                                              u16* __restrict__ HT0){
  const int tid = blockIdx.x*256 + threadIdx.x;   // < 131072
  const int b = tid >> 10, m = tid & 1023;
  HT0[tid] = f2bf(hp[(size_t)m*NB + b]);
}

// ---------------- X [T][IN][B] fp32 -> X^T [T][B][IN] bf16 ----------------
__global__ __launch_bounds__(256) void xT_k(const float* __restrict__ x,
                                            u16* __restrict__ xt){
  __shared__ float tile[64][65];
  const int t  = blockIdx.z;
  const int k0 = blockIdx.y*64;
  const int b0 = blockIdx.x*64;
  const int tx = threadIdx.x & 63, ty = threadIdx.x >> 6;  // ty 0..3
  const float* src = x + (size_t)t*DIN*NB + (size_t)k0*NB + b0;
#pragma unroll
  for(int r=0;r<16;r++){ int k = r*4 + ty; tile[k][tx] = src[(size_t)k*NB + tx]; }
  __syncthreads();
  u16* dst = xt + (size_t)t*NB*DIN + (size_t)b0*DIN + k0;
#pragma unroll
  for(int r=0;r<16;r++){ int b = r*4 + ty; dst[(size_t)b*DIN + tx] = f2bf(tile[tx][b]); }
}

// ---------------- A[t] = X^T[t] @ Wxh^T + bh  -> bf16 [T][B][HID] ----------------
__global__ __launch_bounds__(256) void gemm_xw(const u16* __restrict__ XT,
                                               const u16* __restrict__ WxB,
                                               const float* __restrict__ bh,
                                               u16* __restrict__ AT){
  const int t  = blockIdx.y;
  const int mj = blockIdx.x;
  __shared__ __align__(16) u16 As[128*40];
  __shared__ __align__(16) u16 Bs[128*40];
  const u16* aG = XT + (size_t)t*NB*DIN;          // rows = b (128), K-contig
  const u16* bG = WxB + (size_t)mj*128*DIN;       // rows = m slice, K-contig
  const int tid = threadIdx.x;
  const int lane = tid & 63, w = tid >> 6;
  const int wr = (w & 1)*64, wc = (w >> 1)*64;
  const int l15 = lane & 15, q = lane >> 4;
  const int sr = tid >> 2;            // 0..63
  const int sk = (tid & 3)*8;         // 0,8,16,24

  f32x4 acc[4][4] = {};
  uint4 pa0 = *(const uint4*)&aG[(size_t)sr*DIN + sk];
  uint4 pa1 = *(const uint4*)&aG[(size_t)(sr+64)*DIN + sk];
  uint4 pb0 = *(const uint4*)&bG[(size_t)sr*DIN + sk];
  uint4 pb1 = *(const uint4*)&bG[(size_t)(sr+64)*DIN + sk];

  for(int it = 0; it < DIN/32; ++it){
    __syncthreads();
    *(uint4*)&As[sr*40 + sk]      = pa0;
    *(uint4*)&As[(sr+64)*40 + sk] = pa1;
    *(uint4*)&Bs[sr*40 + sk]      = pb0;
    *(uint4*)&Bs[(sr+64)*40 + sk] = pb1;
    __syncthreads();
    if(it < DIN/32 - 1){
      const int k0 = (it+1)*32;
      pa0 = *(const uint4*)&aG[(size_t)sr*DIN + k0 + sk];
      pa1 = *(const uint4*)&aG[(size_t)(sr+64)*DIN + k0 + sk];
      pb0 = *(const uint4*)&bG[(size_t)sr*DIN + k0 + sk];
      pb1 = *(const uint4*)&bG[(size_t)(sr+64)*DIN + k0 + sk];
    }
    bf16x8 af[4], bf[4];
#pragma unroll
    for(int i=0;i<4;i++) af[i] = *(const bf16x8*)&As[(wr + i*16 + l15)*40 + q*8];
#pragma unroll
    for(int j=0;j<4;j++) bf[j] = *(const bf16x8*)&Bs[(wc + j*16 + l15)*40 + q*8];
#pragma unroll
    for(int i=0;i<4;i++)
#pragma unroll
      for(int j=0;j<4;j++)
        acc[i][j] = __builtin_amdgcn_mfma_f32_16x16x32_bf16(af[i], bf[j], acc[i][j], 0,0,0);
  }

  u16* out = AT + (size_t)t*NB*DHID;
#pragma unroll
  for(int j=0;j<4;j++){
    const int mg = mj*128 + wc + j*16 + l15;
    const float bhv = bh[mg];
#pragma unroll
    for(int i=0;i<4;i++){
#pragma unroll
      for(int r=0;r<4;r++){
        const int bg = wr + i*16 + q*4 + r;     // D row = A-operand m-index (=b here)
        out[(size_t)bg*DHID + mg] = f2bf(acc[i][j][r] + bhv);
      }
    }
  }
}

// ---------------- persistent recurrence: all 256 steps in one launch ----------------
// grid = 128 blocks (16 m-slices x 8 b-groups), 256 thr (4 waves).
// Whh fragments pinned in VGPRs (128 VGPRs/lane) for the entire kernel.
// H_prev tile staged through LDS in 4 double-buffered K-chunks of 256.
// Step boundary: device-scope monotone atomic barrier (co-residency: 128 < 256 CUs).
__global__ __launch_bounds__(256, 1) void rnn_steps(const u16* __restrict__ WhB,
                                                    const u16* __restrict__ AT,
                                                    u16* __restrict__ HT,
                                                    u32* bar){
  const int mslice = blockIdx.x & 15;   // m_tile = 64
  const int bg     = blockIdx.x >> 4;   // b_tile = 16
  __shared__ __align__(16) u16 Hs[2][16*264];   // 16 rows x 256 k-chunk, pad +8 (2-way max = free)
  const int tid = threadIdx.x;
  const int lane = tid & 63, w = tid >> 6;
  const int l15 = lane & 15, q = lane >> 4, q8 = q*8;
  const int mw = mslice*64 + w*16;      // wave's m sub-slice base

  // ---- load Whh B-fragments into registers, once ----
  bf16x8 wf[32];
  { const u16* wsrc = WhB + (size_t)(mw + l15)*DHID;
#pragma unroll
    for(int i=0;i<32;i++) wf[i] = *(const bf16x8*)&wsrc[i*32 + q8];
  }

  // staging indices: 16 rows x (2x 128 k) per chunk
  const int hr  = tid >> 4;        // 0..15
  const int hk  = (tid & 15)*8;    // 0..120

  for(int t=0; t<T_STEPS; ++t){
    const u16* Hp = HT + (size_t)t*BH + (size_t)bg*16*DHID;
    const u16* At = AT + (size_t)t*BH;

    // epilogue addend, issued early
    u16 aval[4];
#pragma unroll
    for(int r=0;r<4;r++)
      aval[r] = At[(size_t)(bg*16 + q*4 + r)*DHID + mw + l15];

    uint4 p0 = *(const uint4*)&Hp[(size_t)hr*DHID + hk];
    uint4 p1 = *(const uint4*)&Hp[(size_t)hr*DHID + 128 + hk];

    f32x4 acc = {0.f,0.f,0.f,0.f};
#pragma unroll
    for(int c=0;c<4;c++){
      *(uint4*)&Hs[c&1][hr*264 + hk]       = p0;
      *(uint4*)&Hs[c&1][hr*264 + 128 + hk] = p1;
      __syncthreads();
      if(c < 3){
        p0 = *(const uint4*)&Hp[(size_t)hr*DHID + (c+1)*256 + hk];
        p1 = *(const uint4*)&Hp[(size_t)hr*DHID + (c+1)*256 + 128 + hk];
      }
#pragma unroll
      for(int kk=0;kk<8;kk++){
        bf16x8 a = *(const bf16x8*)&Hs[c&1][l15*264 + kk*32 + q8];
        acc = __builtin_amdgcn_mfma_f32_16x16x32_bf16(a, wf[c*8+kk], acc, 0,0,0);
      }
    }

    // epilogue: tanh(acc + A) -> H_{t+1}
    u16* Hn = HT + (size_t)(t+1)*BH;
#pragma unroll
    for(int r=0;r<4;r++){
      float v = acc[r] + bf2f(aval[r]);
      Hn[(size_t)(bg*16 + q*4 + r)*DHID + mw + l15] = f2bf(tanhf(v));
    }

    if(t < T_STEPS-1){
      __threadfence();          // release H writes to agent scope (cross-XCD)
      __syncthreads();
      if(tid == 0){
        __hip_atomic_fetch_add(bar, 1u, __ATOMIC_RELEASE, __HIP_MEMORY_SCOPE_AGENT);
        const u32 tgt = (u32)(t+1)*128u;
        while(__hip_atomic_load(bar, __ATOMIC_ACQUIRE, __HIP_MEMORY_SCOPE_AGENT) < tgt)
          __builtin_amdgcn_s_sleep(1);
      }
      __syncthreads();
      __threadfence();          // acquire side for all threads
    }
  }
}

// ---------------- Y[t] = Why @ h_t + by  -> fp32 [T][OUT][B] ----------------
__global__ __launch_bounds__(256) void gemm_hy(const u16* __restrict__ WyB,
                                               const u16* __restrict__ HT,
                                               const float* __restrict__ by,
                                               float* __restrict__ Y){
  const int t  = blockIdx.y;
  const int mi = blockIdx.x;
  __shared__ __align__(16) u16 As[128*40];
  __shared__ __align__(16) u16 Bs[128*40];
  const u16* aG = WyB + (size_t)mi*128*DHID;       // rows = out slice
  const u16* bG = HT  + (size_t)(t+1)*BH;          // rows = b (128)
  const int tid = threadIdx.x;
  const int lane = tid & 63, w = tid >> 6;
  const int wr = (w & 1)*64, wc = (w >> 1)*64;
  const int l15 = lane & 15, q = lane >> 4;
  const int sr = tid >> 2;
  const int sk = (tid & 3)*8;

  f32x4 acc[4][4] = {};
  uint4 pa0 = *(const uint4*)&aG[(size_t)sr*DHID + sk];
  uint4 pa1 = *(const uint4*)&aG[(size_t)(sr+64)*DHID + sk];
  uint4 pb0 = *(const uint4*)&bG[(size_t)sr*DHID + sk];
  uint4 pb1 = *(const uint4*)&bG[(size_t)(sr+64)*DHID + sk];

  for(int it = 0; it < DHID/32; ++it){
    __syncthreads();
    *(uint4*)&As[sr*40 + sk]      = pa0;
    *(uint4*)&As[(sr+64)*40 + sk] = pa1;
    *(uint4*)&Bs[sr*40 + sk]      = pb0;
    *(uint4*)&Bs[(sr+64)*40 + sk] = pb1;
    __syncthreads();
    if(it < DHID/32 - 1){
      const int k0 = (it+1)*32;
      pa0 = *(const uint4*)&aG[(size_t)sr*DHID + k0 + sk];
      pa1 = *(const uint4*)&aG[(size_t)(sr+64)*DHID + k0 + sk];
      pb0 = *(const uint4*)&bG[(size_t)sr*DHID + k0 + sk];
      pb1 = *(const uint4*)&bG[(size_t)(sr+64)*DHID + k0 + sk];
    }
    bf16x8 af[4], bf[4];
#pragma unroll
    for(int i=0;i<4;i++) af[i] = *(const bf16x8*)&As[(wr + i*16 + l15)*40 + q*8];
#pragma unroll
    for(int j=0;j<4;j++) bf[j] = *(const bf16x8*)&Bs[(wc + j*16 + l15)*40 + q*8];
#pragma unroll
    for(int i=0;i<4;i++)
#pragma unroll
      for(int j=0;j<4;j++)
        acc[i][j] = __builtin_amdgcn_mfma_f32_16x16x32_bf16(af[i], bf[j], acc[i][j], 0,0,0);
  }

  float* out = Y + (size_t)t*DOUT*NB;
#pragma unroll
  for(int i=0;i<4;i++){
#pragma unroll
    for(int r=0;r<4;r++){
      const int og = mi*128 + wr + i*16 + q*4 + r;  // D row = out index
      const float byv = by[og];
#pragma unroll
      for(int j=0;j<4;j++){
        const int bg = wc + j*16 + l15;             // D col = batch index
        out[(size_t)og*NB + bg] = acc[i][j][r] + byv;
      }
    }
  }
}

// ---------------- h_final: H_T[T] [B][HID] bf16 -> [HID][B] fp32 ----------------
__global__ __launch_bounds__(256) void hfinal(const u16* __restrict__ HT,
                                              float* __restrict__ dst){
  const int tid = blockIdx.x*256 + threadIdx.x;   // < 131072
  const int m = tid >> 7, b = tid & 127;
  dst[tid] = bf2f(HT[(size_t)T_STEPS*BH + (size_t)b*DHID + m]);
}

extern "C" void kernel_launch(void* const* d_in, const int* in_sizes, int n_in,
                              void* d_out, int out_size, void* d_ws, size_t ws_size,
                              hipStream_t stream)
{
  const float* x   = (const float*)d_in[0];   // [T, IN, B]
  const float* hp  = (const float*)d_in[1];   // [HID, B]
  const float* wxh = (const float*)d_in[2];   // [HID, IN]
  const float* whh = (const float*)d_in[3];   // [HID, HID]
  const float* why = (const float*)d_in[4];   // [OUT, HID]
  const float* bh  = (const float*)d_in[5];   // [HID, 1]
  const float* by  = (const float*)d_in[6];   // [OUT, 1]
  float* out = (float*)d_out;

  // workspace: bf16 weights (6 MB) + H_T (T+1 snapshots, 64.25 MB) + barrier
  u16* WxB = (u16*)d_ws;
  u16* WhB = WxB + (size_t)1024*1024;
  u16* WyB = WhB + (size_t)1024*1024;
  u16* HT  = WyB + (size_t)1024*1024;
  u32* bar = (u32*)(HT + (size_t)(T_STEPS+1)*BH);

  // temporaries inside d_out (dead before gemm_hy overwrites):
  u16* XT = (u16*)d_out;
  u16* AT = XT + (size_t)T_STEPS*NB*DIN;

  wconv  <<<3072, 256, 0, stream>>>(wxh, whh, why, WxB);
  hprevT <<<512,  256, 0, stream>>>(hp, HT);
  xT_k   <<<dim3(2,16,T_STEPS), 256, 0, stream>>>(x, XT);
  gemm_xw<<<dim3(8,T_STEPS),    256, 0, stream>>>(XT, WxB, bh, AT);
  hipMemsetAsync(bar, 0, 64, stream);
  rnn_steps<<<128, 256, 0, stream>>>(WhB, AT, HT, bar);
  gemm_hy<<<dim3(8,T_STEPS), 256, 0, stream>>>(WyB, HT, by, out);
  hfinal <<<512, 256, 0, stream>>>(HT, out + (size_t)T_STEPS*DOUT*NB);
}

// Round 3
// 1498.932 us; speedup vs baseline: 4.5223x; 4.5223x over previous
//
#include <hip/hip_runtime.h>
#include <cmath>

#define T_STEPS 256
#define DIN  1024
#define DHID 1024
#define DOUT 1024
#define NB   128
#define BH   (DHID*NB)   // 131072 elems per h snapshot

typedef unsigned short u16;
typedef unsigned int   u32;
typedef unsigned long long u64;
typedef __attribute__((ext_vector_type(8))) __bf16 bf16x8;
typedef __attribute__((ext_vector_type(4))) float  f32x4;

__device__ __forceinline__ u16 f2bf(float f){
  u32 u = __builtin_bit_cast(u32, f);
  u32 r = (u + 0x7fffu + ((u >> 16) & 1u)) >> 16;   // RNE
  return (u16)r;
}
__device__ __forceinline__ float bf2f(u16 h){
  u32 u = ((u32)h) << 16;
  return __builtin_bit_cast(float, u);
}

// agent-scope (cross-XCD-coherent) accesses: sc0 sc1, bypass non-coherent L2,
// coherence point = shared L3. No cache-flush fences needed anywhere.
__device__ __forceinline__ void st_agent_u16(u16* p, u16 v){
  __hip_atomic_store(p, v, __ATOMIC_RELAXED, __HIP_MEMORY_SCOPE_AGENT);
}
__device__ __forceinline__ u64 ld_agent_u64(const u64* p){
  return __hip_atomic_load(p, __ATOMIC_RELAXED, __HIP_MEMORY_SCOPE_AGENT);
}

// ---------------- weight convert: 3x 1024x1024 fp32 -> bf16 ----------------
__global__ __launch_bounds__(256) void wconv(const float* __restrict__ w0,
                                             const float* __restrict__ w1,
                                             const float* __restrict__ w2,
                                             u16* __restrict__ dst){
  const int idx = blockIdx.x*256 + threadIdx.x;   // < 786432 (float4 units)
  const int seg = idx >> 18;                      // /262144
  const int off = idx & 262143;
  const float* src = seg==0 ? w0 : (seg==1 ? w1 : w2);
  const float4 v = ((const float4*)src)[off];
  ushort4 o = make_ushort4(f2bf(v.x), f2bf(v.y), f2bf(v.z), f2bf(v.w));
  ((ushort4*)dst)[idx] = o;
}

// ---------------- h_prev [HID][B] fp32 -> H_T[0] [B][HID] bf16 ----------------
__global__ __launch_bounds__(256) void hprevT(const float* __restrict__ hp,
                                              u16* __restrict__ HT0){
  const int tid = blockIdx.x*256 + threadIdx.x;   // < 131072
  const int b = tid >> 10, m = tid & 1023;
  HT0[tid] = f2bf(hp[(size_t)m*NB + b]);
}

// ---------------- X [T][IN][B] fp32 -> X^T [T][B][IN] bf16 ----------------
__global__ __launch_bounds__(256) void xT_k(const float* __restrict__ x,
                                            u16* __restrict__ xt){
  __shared__ float tile[64][65];
  const int t  = blockIdx.z;
  const int k0 = blockIdx.y*64;
  const int b0 = blockIdx.x*64;
  const int tx = threadIdx.x & 63, ty = threadIdx.x >> 6;  // ty 0..3
  const float* src = x + (size_t)t*DIN*NB + (size_t)k0*NB + b0;
#pragma unroll
  for(int r=0;r<16;r++){ int k = r*4 + ty; tile[k][tx] = src[(size_t)k*NB + tx]; }
  __syncthreads();
  u16* dst = xt + (size_t)t*NB*DIN + (size_t)b0*DIN + k0;
#pragma unroll
  for(int r=0;r<16;r++){ int b = r*4 + ty; dst[(size_t)b*DIN + tx] = f2bf(tile[tx][b]); }
}

// ---------------- A[t] = X^T[t] @ Wxh^T + bh  -> bf16 [T][B][HID] ----------------
__global__ __launch_bounds__(256) void gemm_xw(const u16* __restrict__ XT,
                                               const u16* __restrict__ WxB,
                                               const float* __restrict__ bh,
                                               u16* __restrict__ AT){
  const int t  = blockIdx.y;
  const int mj = blockIdx.x;
  __shared__ __align__(16) u16 As[128*40];
  __shared__ __align__(16) u16 Bs[128*40];
  const u16* aG = XT + (size_t)t*NB*DIN;          // rows = b (128), K-contig
  const u16* bG = WxB + (size_t)mj*128*DIN;       // rows = m slice, K-contig
  const int tid = threadIdx.x;
  const int lane = tid & 63, w = tid >> 6;
  const int wr = (w & 1)*64, wc = (w >> 1)*64;
  const int l15 = lane & 15, q = lane >> 4;
  const int sr = tid >> 2;            // 0..63
  const int sk = (tid & 3)*8;         // 0,8,16,24

  f32x4 acc[4][4] = {};
  uint4 pa0 = *(const uint4*)&aG[(size_t)sr*DIN + sk];
  uint4 pa1 = *(const uint4*)&aG[(size_t)(sr+64)*DIN + sk];
  uint4 pb0 = *(const uint4*)&bG[(size_t)sr*DIN + sk];
  uint4 pb1 = *(const uint4*)&bG[(size_t)(sr+64)*DIN + sk];

  for(int it = 0; it < DIN/32; ++it){
    __syncthreads();
    *(uint4*)&As[sr*40 + sk]      = pa0;
    *(uint4*)&As[(sr+64)*40 + sk] = pa1;
    *(uint4*)&Bs[sr*40 + sk]      = pb0;
    *(uint4*)&Bs[(sr+64)*40 + sk] = pb1;
    __syncthreads();
    if(it < DIN/32 - 1){
      const int k0 = (it+1)*32;
      pa0 = *(const uint4*)&aG[(size_t)sr*DIN + k0 + sk];
      pa1 = *(const uint4*)&aG[(size_t)(sr+64)*DIN + k0 + sk];
      pb0 = *(const uint4*)&bG[(size_t)sr*DIN + k0 + sk];
      pb1 = *(const uint4*)&bG[(size_t)(sr+64)*DIN + k0 + sk];
    }
    bf16x8 af[4], bf[4];
#pragma unroll
    for(int i=0;i<4;i++) af[i] = *(const bf16x8*)&As[(wr + i*16 + l15)*40 + q*8];
#pragma unroll
    for(int j=0;j<4;j++) bf[j] = *(const bf16x8*)&Bs[(wc + j*16 + l15)*40 + q*8];
#pragma unroll
    for(int i=0;i<4;i++)
#pragma unroll
      for(int j=0;j<4;j++)
        acc[i][j] = __builtin_amdgcn_mfma_f32_16x16x32_bf16(af[i], bf[j], acc[i][j], 0,0,0);
  }

  u16* out = AT + (size_t)t*NB*DHID;
#pragma unroll
  for(int j=0;j<4;j++){
    const int mg = mj*128 + wc + j*16 + l15;
    const float bhv = bh[mg];
#pragma unroll
    for(int i=0;i<4;i++){
#pragma unroll
      for(int r=0;r<4;r++){
        const int bg = wr + i*16 + q*4 + r;     // D row = A-operand m-index (=b here)
        out[(size_t)bg*DHID + mg] = f2bf(acc[i][j][r] + bhv);
      }
    }
  }
}

// ---------------- persistent recurrence: all 256 steps in one launch ----------------
// grid = 64 blocks (8 m-slices x 8 b-groups) x 512 thr (8 waves).
// Whh fragments pinned in AGPR/VGPR for the entire kernel (32 x bf16x8 per lane).
// H exchanged via agent-scope (sc0 sc1) loads/stores -> coherent at shared L3,
// so the per-step barrier needs NO cache-flushing fences.
#define RSTEP_BLOCKS 64
__global__ __launch_bounds__(512, 1) void rnn_steps(const u16* __restrict__ WhB,
                                                    const u16* __restrict__ AT,
                                                    u16* __restrict__ HT,
                                                    u32* bar){
  const int mslice = blockIdx.x & 7;    // m_tile = 128 (16 per wave)
  const int bg     = blockIdx.x >> 3;   // b_tile = 16
  __shared__ __align__(16) u16 Hs[16*1032];   // 16 rows x 1024, pad +8 (2-way = free)
  const int tid = threadIdx.x;
  const int lane = tid & 63, w = tid >> 6;    // w 0..7
  const int l15 = lane & 15, q = lane >> 4, q8 = q*8;
  const int mw = mslice*128 + w*16;           // wave's m sub-slice base

  // ---- load Whh B-fragments into registers, once ----
  bf16x8 wf[32];
  { const u16* wsrc = WhB + (size_t)(mw + l15)*DHID;
#pragma unroll
    for(int i=0;i<32;i++) wf[i] = *(const bf16x8*)&wsrc[i*32 + q8];
  }

  // staging: 512 thr, 16 rows x 256 u64 per row. thread -> row tid>>5, u64 col (tid&31)+i*32
  const int hr  = tid >> 5;        // 0..15
  const int hc  = tid & 31;        // u64 col base

  for(int t=0; t<T_STEPS; ++t){
    const u64* Hp64 = (const u64*)(HT + (size_t)t*BH + (size_t)(bg*16 + hr)*DHID) + hc;

    // issue coherent H loads first (longest latency)
    u64 hv[8];
#pragma unroll
    for(int i=0;i<8;i++) hv[i] = ld_agent_u64(Hp64 + i*32);

    // epilogue addend (read-only, plain cached loads)
    const u16* At = AT + (size_t)t*BH;
    u16 aval[4];
#pragma unroll
    for(int r=0;r<4;r++)
      aval[r] = At[(size_t)(bg*16 + q*4 + r)*DHID + mw + l15];

    u64* hs64 = (u64*)&Hs[hr*1032] + hc;
#pragma unroll
    for(int i=0;i<8;i++) hs64[i*32] = hv[i];
    __syncthreads();

    f32x4 acc = {0.f,0.f,0.f,0.f};
#pragma unroll
    for(int kk=0;kk<32;kk++){
      bf16x8 a = *(const bf16x8*)&Hs[l15*1032 + kk*32 + q8];
      acc = __builtin_amdgcn_mfma_f32_16x16x32_bf16(a, wf[kk], acc, 0,0,0);
    }

    // epilogue: tanh(acc + A) -> H_{t+1} via coherent stores
    u16* Hn = HT + (size_t)(t+1)*BH;
#pragma unroll
    for(int r=0;r<4;r++){
      float v = acc[r] + bf2f(aval[r]);
      st_agent_u16(&Hn[(size_t)(bg*16 + q*4 + r)*DHID + mw + l15], f2bf(tanhf(v)));
    }

    if(t < T_STEPS-1){
      // stores are sc0sc1: once vmcnt drains they are at the coherence point (L3).
      asm volatile("s_waitcnt vmcnt(0)" ::: "memory");
      __syncthreads();     // also protects Hs reuse next iteration
      if(tid == 0){
        __hip_atomic_fetch_add(bar, 1u, __ATOMIC_RELAXED, __HIP_MEMORY_SCOPE_AGENT);
        const u32 tgt = (u32)(t+1)*RSTEP_BLOCKS;
        while(__hip_atomic_load(bar, __ATOMIC_RELAXED, __HIP_MEMORY_SCOPE_AGENT) < tgt)
          __builtin_amdgcn_s_sleep(2);
      }
      __syncthreads();
    }
  }
}

// ---------------- Y[t] = Why @ h_t + by  -> fp32 [T][OUT][B] ----------------
__global__ __launch_bounds__(256) void gemm_hy(const u16* __restrict__ WyB,
                                               const u16* __restrict__ HT,
                                               const float* __restrict__ by,
                                               float* __restrict__ Y){
  const int t  = blockIdx.y;
  const int mi = blockIdx.x;
  __shared__ __align__(16) u16 As[128*40];
  __shared__ __align__(16) u16 Bs[128*40];
  const u16* aG = WyB + (size_t)mi*128*DHID;       // rows = out slice
  const u16* bG = HT  + (size_t)(t+1)*BH;          // rows = b (128)
  const int tid = threadIdx.x;
  const int lane = tid & 63, w = tid >> 6;
  const int wr = (w & 1)*64, wc = (w >> 1)*64;
  const int l15 = lane & 15, q = lane >> 4;
  const int sr = tid >> 2;
  const int sk = (tid & 3)*8;

  f32x4 acc[4][4] = {};
  uint4 pa0 = *(const uint4*)&aG[(size_t)sr*DHID + sk];
  uint4 pa1 = *(const uint4*)&aG[(size_t)(sr+64)*DHID + sk];
  uint4 pb0 = *(const uint4*)&bG[(size_t)sr*DHID + sk];
  uint4 pb1 = *(const uint4*)&bG[(size_t)(sr+64)*DHID + sk];

  for(int it = 0; it < DHID/32; ++it){
    __syncthreads();
    *(uint4*)&As[sr*40 + sk]      = pa0;
    *(uint4*)&As[(sr+64)*40 + sk] = pa1;
    *(uint4*)&Bs[sr*40 + sk]      = pb0;
    *(uint4*)&Bs[(sr+64)*40 + sk] = pb1;
    __syncthreads();
    if(it < DHID/32 - 1){
      const int k0 = (it+1)*32;
      pa0 = *(const uint4*)&aG[(size_t)sr*DHID + k0 + sk];
      pa1 = *(const uint4*)&aG[(size_t)(sr+64)*DHID + k0 + sk];
      pb0 = *(const uint4*)&bG[(size_t)sr*DHID + k0 + sk];
      pb1 = *(const uint4*)&bG[(size_t)(sr+64)*DHID + k0 + sk];
    }
    bf16x8 af[4], bf[4];
#pragma unroll
    for(int i=0;i<4;i++) af[i] = *(const bf16x8*)&As[(wr + i*16 + l15)*40 + q*8];
#pragma unroll
    for(int j=0;j<4;j++) bf[j] = *(const bf16x8*)&Bs[(wc + j*16 + l15)*40 + q*8];
#pragma unroll
    for(int i=0;i<4;i++)
#pragma unroll
      for(int j=0;j<4;j++)
        acc[i][j] = __builtin_amdgcn_mfma_f32_16x16x32_bf16(af[i], bf[j], acc[i][j], 0,0,0);
  }

  float* out = Y + (size_t)t*DOUT*NB;
#pragma unroll
  for(int i=0;i<4;i++){
#pragma unroll
    for(int r=0;r<4;r++){
      const int og = mi*128 + wr + i*16 + q*4 + r;  // D row = out index
      const float byv = by[og];
#pragma unroll
      for(int j=0;j<4;j++){
        const int bg = wc + j*16 + l15;             // D col = batch index
        out[(size_t)og*NB + bg] = acc[i][j][r] + byv;
      }
    }
  }
}

// ---------------- h_final: H_T[T] [B][HID] bf16 -> [HID][B] fp32 ----------------
__global__ __launch_bounds__(256) void hfinal(const u16* __restrict__ HT,
                                              float* __restrict__ dst){
  const int tid = blockIdx.x*256 + threadIdx.x;   // < 131072
  const int m = tid >> 7, b = tid & 127;
  dst[tid] = bf2f(HT[(size_t)T_STEPS*BH + (size_t)b*DHID + m]);
}

extern "C" void kernel_launch(void* const* d_in, const int* in_sizes, int n_in,
                              void* d_out, int out_size, void* d_ws, size_t ws_size,
                              hipStream_t stream)
{
  const float* x   = (const float*)d_in[0];   // [T, IN, B]
  const float* hp  = (const float*)d_in[1];   // [HID, B]
  const float* wxh = (const float*)d_in[2];   // [HID, IN]
  const float* whh = (const float*)d_in[3];   // [HID, HID]
  const float* why = (const float*)d_in[4];   // [OUT, HID]
  const float* bh  = (const float*)d_in[5];   // [HID, 1]
  const float* by  = (const float*)d_in[6];   // [OUT, 1]
  float* out = (float*)d_out;

  // workspace: bf16 weights (6 MB) + H_T (T+1 snapshots, 64.25 MB) + barrier
  u16* WxB = (u16*)d_ws;
  u16* WhB = WxB + (size_t)1024*1024;
  u16* WyB = WhB + (size_t)1024*1024;
  u16* HT  = WyB + (size_t)1024*1024;
  u32* bar = (u32*)(HT + (size_t)(T_STEPS+1)*BH);

  // temporaries inside d_out (dead before gemm_hy overwrites):
  u16* XT = (u16*)d_out;
  u16* AT = XT + (size_t)T_STEPS*NB*DIN;

  wconv  <<<3072, 256, 0, stream>>>(wxh, whh, why, WxB);
  hprevT <<<512,  256, 0, stream>>>(hp, HT);
  xT_k   <<<dim3(2,16,T_STEPS), 256, 0, stream>>>(x, XT);
  gemm_xw<<<dim3(8,T_STEPS),    256, 0, stream>>>(XT, WxB, bh, AT);
  hipMemsetAsync(bar, 0, 64, stream);
  rnn_steps<<<RSTEP_BLOCKS, 512, 0, stream>>>(WhB, AT, HT, bar);
  gemm_hy<<<dim3(8,T_STEPS), 256, 0, stream>>>(WyB, HT, by, out);
  hfinal <<<512, 256, 0, stream>>>(HT, out + (size_t)T_STEPS*DOUT*NB);
}